// Round 2
// baseline (127.705 us; speedup 1.0000x reference)
//
#include <hip/hip_runtime.h>
#include <math.h>

#define NCODES 16
#define NHALF 8
#define LOG2E 1.4426950408889634f

typedef float f32x4 __attribute__((ext_vector_type(4)));

// Force a wave-uniform float into an SGPR (exact: value identical on all lanes).
__device__ __forceinline__ float rfl(float v) {
    return __int_as_float(__builtin_amdgcn_readfirstlane(__float_as_int(v)));
}

// ThermoQuantizer: per-128-group abs-mean scale, soft-quantize to uniform
// 16-level codebook via softmax over -(x_norm-c)^2/T, lerp with pressure.
//
// Algebraic collapse (codebook = linspace(-1,1,16), uniform & symmetric):
//   prob_i ∝ exp((2 x c_i - c_i^2)/T)  (x^2 term cancels in softmax)
// For x>=0, with codes C_j = cb[15-j] (descending from +1):
//   term_j = W_j * q^j,  W_j = exp(-C_j^2/T),  q = exp(-2|xn|*step/T) in (0,1]
// Even/odd Horner split in q2: num = En(q2)+q*On(q2), den = Ed(q2)+q*Od(q2).
// x<0 by odd symmetry (copysign).
//
// v3 (vs the 116.7us v1): R1 proved the LDS-LUT path regresses (random-gather
// bank conflicts > VALU saved), i.e. v1 was NOT VALU-throughput-bound.
// Theory: v1's 32 VGPRs of wave-uniform table constants pushed it past the
// 64-VGPR cliff -> 4 waves/SIMD -> latency-bound at ~66% of the copy roofline.
// Fix: readfirstlane the tables into SGPRs (v_fma_f32 takes 1 SGPR operand),
// __launch_bounds__(256,8) for 8 waves/SIMD, and a 2-deep unroll so each wave
// keeps two independent float4 streams in flight across the ~400cy body.
__global__ __launch_bounds__(256, 8) void tq_kernel(
    const float* __restrict__ x,
    const float* __restrict__ cb,
    const float* __restrict__ pp,
    const float* __restrict__ tp,
    float* __restrict__ out,
    int n4)
{
    const float pressure = rfl(pp[0]);
    const float invT = rfl(1.0f / (tp[0] + 1e-6f));

    // Per-wave code tables in SGPRs (even/odd in power index j), j-th code
    // (for x>=0): C_j = cb[15-j].
    float WE[NHALF], WO[NHALF], WCE[NHALF], WCO[NHALF];
#pragma unroll
    for (int h = 0; h < NHALF; ++h) {
        float ce = rfl(cb[NCODES - 1 - 2 * h]);   // j = 2h
        float co = rfl(cb[NCODES - 2 - 2 * h]);   // j = 2h+1
        float we = exp2f(-ce * ce * invT * LOG2E);
        float wo = exp2f(-co * co * invT * LOG2E);
        WE[h] = rfl(we);  WCE[h] = rfl(we * ce);
        WO[h] = rfl(wo);  WCO[h] = rfl(wo * co);
    }
    const float step = rfl((cb[NCODES - 1] - cb[0]) * (1.0f / 15.0f));
    const float kq = rfl(2.0f * step * invT * LOG2E);  // q = exp2(-|xn| * kq)

    const int stride = gridDim.x * blockDim.x;

    // Process one float4 (group = 128 floats = 32 consecutive lanes x float4).
    auto process = [&](f32x4 v) -> f32x4 {
        float a = fabsf(v.x) + fabsf(v.y) + fabsf(v.z) + fabsf(v.w);
#pragma unroll
        for (int m = 1; m <= 16; m <<= 1)
            a += __shfl_xor(a, m, 64);  // masks <32: stays within 32-lane half

        const float mean_c   = fmaxf(a * (1.0f / 128.0f), 1e-5f);
        const float inv_mean = __builtin_amdgcn_rcpf(mean_c);

        f32x4 o;
#pragma unroll
        for (int e = 0; e < 4; ++e) {
            float xv = v[e];
            float xn = fabsf(xv) * inv_mean;
            float q  = exp2f(-xn * kq);
            float q2 = q * q;
            // 4 independent Horner chains of 7 fmas each (SGPR coefficients).
            float en = WCE[NHALF - 1], on = WCO[NHALF - 1];
            float ed = WE[NHALF - 1],  od = WO[NHALF - 1];
#pragma unroll
            for (int h = NHALF - 2; h >= 0; --h) {
                en = fmaf(en, q2, WCE[h]);
                on = fmaf(on, q2, WCO[h]);
                ed = fmaf(ed, q2, WE[h]);
                od = fmaf(od, q2, WO[h]);
            }
            float num = fmaf(q, on, en);
            float den = fmaf(q, od, ed);
            float qn = num * __builtin_amdgcn_rcpf(den);  // qx_norm for |x|
            qn = copysignf(qn, xv);                        // odd symmetry
            float qx = qn * mean_c;                        // un-normalize
            o[e] = fmaf(pressure, qx - xv, xv);            // lerp
        }
        return o;
    };

    int i = blockIdx.x * blockDim.x + threadIdx.x;
    // 2-deep unrolled main loop: two independent float4 streams in flight.
    for (; i + stride < n4; i += 2 * stride) {
        f32x4 va = reinterpret_cast<const f32x4*>(x)[i];
        f32x4 vb = reinterpret_cast<const f32x4*>(x)[i + stride];
        f32x4 oa = process(va);
        f32x4 ob = process(vb);
        __builtin_nontemporal_store(oa, reinterpret_cast<f32x4*>(out) + i);
        __builtin_nontemporal_store(ob, reinterpret_cast<f32x4*>(out) + i + stride);
    }
    for (; i < n4; i += stride) {
        f32x4 v = reinterpret_cast<const f32x4*>(x)[i];
        f32x4 o = process(v);
        __builtin_nontemporal_store(o, reinterpret_cast<f32x4*>(out) + i);
    }
}

extern "C" void kernel_launch(void* const* d_in, const int* in_sizes, int n_in,
                              void* d_out, int out_size, void* d_ws, size_t ws_size,
                              hipStream_t stream)
{
    const float* x  = (const float*)d_in[0];
    const float* cb = (const float*)d_in[1];
    const float* pp = (const float*)d_in[2];  // pressure (1-elem array)
    const float* tp = (const float*)d_in[3];  // temp (1-elem array)
    float* out = (float*)d_out;

    int n4 = in_sizes[0] / 4;   // 4194304 float4s; multiple of 32 => groups align
    dim3 grid(2048), block(256);
    hipLaunchKernelGGL(tq_kernel, grid, block, 0, stream,
                       x, cb, pp, tp, out, n4);
}

// Round 3
// 115.803 us; speedup vs baseline: 1.1028x; 1.1028x over previous
//
#include <hip/hip_runtime.h>
#include <math.h>

#define NCODES 16
#define NHALF 8
#define LOG2E 1.4426950408889634f

typedef float f32x4 __attribute__((ext_vector_type(4)));

// ThermoQuantizer: per-128-group abs-mean scale, soft-quantize to uniform
// 16-level codebook via softmax over -(x_norm-c)^2/T, lerp with pressure.
//
// Algebraic collapse (codebook = linspace(-1,1,16), uniform & symmetric):
//   prob_i ∝ exp((2 x c_i - c_i^2)/T)  (x^2 term cancels in softmax)
// For x>=0, with codes C_j = cb[15-j] (descending from +1):
//   term_j = W_j * q^j,  W_j = exp(-C_j^2/T),  q = exp(-2|xn|*step/T) in (0,1]
// Even/odd Horner split in q2: num = En(q2)+q*On(q2), den = Ed(q2)+q*Od(q2).
// x<0 by odd symmetry (copysign).
//
// v4 (vs 116.7us v1): R1 showed LDS-LUT loses (gather conflicts > VALU saved);
// R2 showed forced occupancy (launch_bounds 8) + far-stride unroll loses
// (spills). VALU arithmetic is only ~10us chip-wide vs 21.3us HBM floor, so
// the v1->ideal gap is memory-pipeline: MLP=1 per wave against a ~1300cy
// dependent chain (load 900cy -> 5-step shuffle reduce -> Horner -> store).
// Fix: group = 16 lanes x 2 float4 (was 32 x 1). Two back-to-back dwordx4
// loads per lane (256B apart, cacheline-aligned 256B runs -> perfect
// coalescing) double bytes-in-flight per wave; reduce drops to 4 shuffle
// steps (masks 1/2/4/8, within 16 lanes). No launch_bounds min-waves, no
// SGPR forcing; +16 VGPRs stays in the same occupancy band.
__global__ __launch_bounds__(256) void tq_kernel(
    const float* __restrict__ x,
    const float* __restrict__ cb,
    const float* __restrict__ pp,
    const float* __restrict__ tp,
    float* __restrict__ out,
    int n4)
{
    const float pressure = pp[0];
    const float invT = 1.0f / (tp[0] + 1e-6f);

    // Per-thread code tables (even/odd in power index j), amortized over the
    // grid-stride loop. j-th code (for x>=0): C_j = cb[15-j].
    float WE[NHALF], WO[NHALF], WCE[NHALF], WCO[NHALF];
#pragma unroll
    for (int h = 0; h < NHALF; ++h) {
        float ce = cb[NCODES - 1 - 2 * h];        // j = 2h
        float co = cb[NCODES - 2 - 2 * h];        // j = 2h+1
        float we = exp2f(-ce * ce * invT * LOG2E);
        float wo = exp2f(-co * co * invT * LOG2E);
        WE[h] = we;  WCE[h] = we * ce;
        WO[h] = wo;  WCO[h] = wo * co;
    }
    const float step = (cb[NCODES - 1] - cb[0]) * (1.0f / 15.0f);
    const float kq = 2.0f * step * invT * LOG2E;   // q = exp2(-|xn| * kq)

    // Soft-quantize one float4 given the group stats.
    auto process = [&](f32x4 v, float mean_c, float inv_mean) -> f32x4 {
        f32x4 o;
#pragma unroll
        for (int e = 0; e < 4; ++e) {
            float xv = v[e];
            float xn = fabsf(xv) * inv_mean;
            float q  = exp2f(-xn * kq);
            float q2 = q * q;
            // 4 independent Horner chains of 7 fmas each.
            float en = WCE[NHALF - 1], on = WCO[NHALF - 1];
            float ed = WE[NHALF - 1],  od = WO[NHALF - 1];
#pragma unroll
            for (int h = NHALF - 2; h >= 0; --h) {
                en = fmaf(en, q2, WCE[h]);
                on = fmaf(on, q2, WCO[h]);
                ed = fmaf(ed, q2, WE[h]);
                od = fmaf(od, q2, WO[h]);
            }
            float num = fmaf(q, on, en);
            float den = fmaf(q, od, ed);
            float qn = num * __builtin_amdgcn_rcpf(den);  // qx_norm for |x|
            qn = copysignf(qn, xv);                        // odd symmetry
            float qx = qn * mean_c;                        // un-normalize
            o[e] = fmaf(pressure, qx - xv, xv);            // lerp
        }
        return o;
    };

    // Group = 128 floats = 32 float4s = 16 lanes x 2 float4s.
    const int tid     = blockIdx.x * blockDim.x + threadIdx.x;
    const int lane16  = threadIdx.x & 15;
    const int ngroups = n4 >> 5;                          // 32 float4 / group
    const int gstride = (gridDim.x * blockDim.x) >> 4;    // groups per pass

    for (int g = tid >> 4; g < ngroups; g += gstride) {
        const int base = g * 32 + lane16;
        // Two independent 16B loads, 256B apart -> MLP=2 per lane.
        f32x4 va = reinterpret_cast<const f32x4*>(x)[base];
        f32x4 vb = reinterpret_cast<const f32x4*>(x)[base + 16];

        float a = fabsf(va.x) + fabsf(va.y) + fabsf(va.z) + fabsf(va.w)
                + fabsf(vb.x) + fabsf(vb.y) + fabsf(vb.z) + fabsf(vb.w);
#pragma unroll
        for (int m = 1; m <= 8; m <<= 1)
            a += __shfl_xor(a, m, 64);   // masks <16: stays within 16 lanes

        const float mean_c   = fmaxf(a * (1.0f / 128.0f), 1e-5f);
        const float inv_mean = __builtin_amdgcn_rcpf(mean_c);

        f32x4 oa = process(va, mean_c, inv_mean);
        f32x4 ob = process(vb, mean_c, inv_mean);
        __builtin_nontemporal_store(oa, reinterpret_cast<f32x4*>(out) + base);
        __builtin_nontemporal_store(ob, reinterpret_cast<f32x4*>(out) + base + 16);
    }
}

extern "C" void kernel_launch(void* const* d_in, const int* in_sizes, int n_in,
                              void* d_out, int out_size, void* d_ws, size_t ws_size,
                              hipStream_t stream)
{
    const float* x  = (const float*)d_in[0];
    const float* cb = (const float*)d_in[1];
    const float* pp = (const float*)d_in[2];  // pressure (1-elem array)
    const float* tp = (const float*)d_in[3];  // temp (1-elem array)
    float* out = (float*)d_out;

    int n4 = in_sizes[0] / 4;   // 4194304 float4s; multiple of 32 => groups align
    dim3 grid(2048), block(256);
    hipLaunchKernelGGL(tq_kernel, grid, block, 0, stream,
                       x, cb, pp, tp, out, n4);
}